// Round 1
// baseline (3506.757 us; speedup 1.0000x reference)
//
#include <hip/hip_runtime.h>

#define NEG_SLOPE 0.2f

// ---------------- edge index width detection (int32 vs int64) ----------------
__device__ __forceinline__ int load_edge(const void* ei, long idx, int is64) {
  if (is64) return (int)((const long long*)ei)[idx];
  return ((const int*)ei)[idx];
}

__global__ void detect64_kernel(const unsigned int* __restrict__ p, int* __restrict__ flag) {
  // int64 little-endian node ids < 2^31 => every odd u32 word is 0.
  int is64 = 1;
  for (int i = 0; i < 32; ++i)
    if (p[2 * i + 1] != 0u) is64 = 0;
  *flag = is64;
}

// ---------------- CSR build ----------------
__global__ void init_cnt_kernel(int* __restrict__ cnt, int n) {
  int i = blockIdx.x * blockDim.x + threadIdx.x;
  if (i < n) cnt[i] = 1;  // self-loop always present
}

__global__ void count_kernel(const void* __restrict__ ei, const int* __restrict__ flag, int E,
                             int* __restrict__ cnt) {
  int e = blockIdx.x * blockDim.x + threadIdx.x;
  if (e >= E) return;
  int is64 = *flag;
  int d = load_edge(ei, (long)E + e, is64);
  atomicAdd(&cnt[d], 1);
}

__global__ __launch_bounds__(1024) void scan_kernel(const int* __restrict__ cnt,
                                                    int* __restrict__ offs, int n) {
  __shared__ int partial[1024];
  int t = threadIdx.x;
  int per = (n + 1023) / 1024;
  int beg = t * per;
  int end = min(beg + per, n);
  int sum = 0;
  for (int i = beg; i < end; ++i) sum += cnt[i];
  partial[t] = sum;
  __syncthreads();
  for (int d = 1; d < 1024; d <<= 1) {
    int v = (t >= d) ? partial[t - d] : 0;
    __syncthreads();
    partial[t] += v;
    __syncthreads();
  }
  int excl = (t == 0) ? 0 : partial[t - 1];
  for (int i = beg; i < end; ++i) { offs[i] = excl; excl += cnt[i]; }
  if (t == 1023) offs[n] = partial[1023];
}

__global__ void init_self_kernel(const int* __restrict__ offs, int* __restrict__ srcs,
                                 int* __restrict__ fill, int n) {
  int i = blockIdx.x * blockDim.x + threadIdx.x;
  if (i < n) { srcs[offs[i]] = i; fill[i] = 1; }
}

__global__ void scatter_kernel(const void* __restrict__ ei, const int* __restrict__ flag, int E,
                               const int* __restrict__ offs, int* __restrict__ fill,
                               int* __restrict__ srcs) {
  int e = blockIdx.x * blockDim.x + threadIdx.x;
  if (e >= E) return;
  int is64 = *flag;
  int s = load_edge(ei, e, is64);
  int d = load_edge(ei, (long)E + e, is64);
  int pos = offs[d] + atomicAdd(&fill[d], 1);
  srcs[pos] = s;
}

// ---------------- fp32 SGEMM: C[M,N] = A[M,K] * B[K,N], row-major ----------------
// Requires K % 16 == 0, N % 128 == 0. M guarded.
#define BM 128
#define BN 128
#define BK 16

__global__ __launch_bounds__(256) void sgemm_kernel(const float* __restrict__ A,
                                                    const float* __restrict__ B,
                                                    float* __restrict__ C, int M, int N, int K) {
  __shared__ float As[BK][BM];
  __shared__ float Bs[BK][BN];
  int tid = threadIdx.x;
  int bm = blockIdx.x * BM;
  int bn = blockIdx.y * BN;
  int tx = tid & 15, ty = tid >> 4;

  float acc[8][8];
#pragma unroll
  for (int i = 0; i < 8; ++i)
#pragma unroll
    for (int j = 0; j < 8; ++j) acc[i][j] = 0.f;

  int arow = tid >> 2;         // 0..63
  int acol = (tid & 3) * 4;    // 0,4,8,12
  int brow = tid >> 5;         // 0..7
  int bcol = (tid & 31) * 4;   // 0..124

  for (int k0 = 0; k0 < K; k0 += BK) {
    // A tile: 128 rows x 16 cols
#pragma unroll
    for (int i = 0; i < 2; ++i) {
      int r = arow + i * 64;
      int gr = bm + r;
      float4 v = make_float4(0.f, 0.f, 0.f, 0.f);
      if (gr < M) v = *(const float4*)&A[(long)gr * K + k0 + acol];
      As[acol + 0][r] = v.x;
      As[acol + 1][r] = v.y;
      As[acol + 2][r] = v.z;
      As[acol + 3][r] = v.w;
    }
    // B tile: 16 rows x 128 cols
#pragma unroll
    for (int i = 0; i < 2; ++i) {
      int r = brow + i * 8;
      float4 v = *(const float4*)&B[(long)(k0 + r) * N + bn + bcol];
      *(float4*)&Bs[r][bcol] = v;
    }
    __syncthreads();
#pragma unroll
    for (int kk = 0; kk < BK; ++kk) {
      float a[8], b[8];
      *(float4*)&a[0] = *(const float4*)&As[kk][ty * 8];
      *(float4*)&a[4] = *(const float4*)&As[kk][ty * 8 + 4];
      *(float4*)&b[0] = *(const float4*)&Bs[kk][tx * 8];
      *(float4*)&b[4] = *(const float4*)&Bs[kk][tx * 8 + 4];
#pragma unroll
      for (int i = 0; i < 8; ++i)
#pragma unroll
        for (int j = 0; j < 8; ++j) acc[i][j] = fmaf(a[i], b[j], acc[i][j]);
    }
    __syncthreads();
  }
#pragma unroll
  for (int i = 0; i < 8; ++i) {
    int gr = bm + ty * 8 + i;
    if (gr < M) {
      float4 v0 = make_float4(acc[i][0], acc[i][1], acc[i][2], acc[i][3]);
      float4 v1 = make_float4(acc[i][4], acc[i][5], acc[i][6], acc[i][7]);
      *(float4*)&C[(long)gr * N + bn + tx * 8] = v0;
      *(float4*)&C[(long)gr * N + bn + tx * 8 + 4] = v1;
    }
  }
}

// ---------------- attention coefficients: a_src/a_dst [N,H] ----------------
__global__ __launch_bounds__(256) void att_coef_kernel(const float* __restrict__ h,
                                                       const float* __restrict__ att_s,
                                                       const float* __restrict__ att_d,
                                                       float* __restrict__ a_s,
                                                       float* __restrict__ a_d, int n, int H,
                                                       int C) {
  int wave = (int)((blockIdx.x * blockDim.x + threadIdx.x) >> 6);
  int lane = threadIdx.x & 63;
  if (wave >= n) return;
  const float* row = h + (long)wave * H * C;
  for (int hh = 0; hh < H; ++hh) {
    float s = 0.f, d = 0.f;
    for (int c = lane; c < C; c += 64) {
      float v = row[hh * C + c];
      s += v * att_s[hh * C + c];
      d += v * att_d[hh * C + c];
    }
#pragma unroll
    for (int o = 32; o > 0; o >>= 1) {
      s += __shfl_down(s, o, 64);
      d += __shfl_down(d, o, 64);
    }
    if (lane == 0) {
      a_s[(long)wave * H + hh] = s;
      a_d[(long)wave * H + hh] = d;
    }
  }
}

// ---------------- per-(dst,head) segment softmax over CSR ----------------
__global__ void edge_softmax_kernel(const float* __restrict__ a_src,
                                    const float* __restrict__ a_dst,
                                    const int* __restrict__ offs, const int* __restrict__ srcs,
                                    float* __restrict__ alpha, int n, int H) {
  int idx = blockIdx.x * blockDim.x + threadIdx.x;
  if (idx >= n * H) return;
  int dstn = idx / H;
  int hh = idx - dstn * H;
  int beg = offs[dstn], end = offs[dstn + 1];
  float ad = a_dst[idx];
  float m = -1e30f;
  for (int j = beg; j < end; ++j) {
    float e = a_src[srcs[j] * H + hh] + ad;
    e = e > 0.f ? e : NEG_SLOPE * e;
    m = fmaxf(m, e);
  }
  float ssum = 0.f;
  for (int j = beg; j < end; ++j) {
    float e = a_src[srcs[j] * H + hh] + ad;
    e = e > 0.f ? e : NEG_SLOPE * e;
    float ex = __expf(e - m);
    alpha[(long)j * H + hh] = ex;
    ssum += ex;
  }
  float inv = 1.f / ssum;
  for (int j = beg; j < end; ++j) alpha[(long)j * H + hh] *= inv;
}

// ---------------- layer-1 aggregation: x2[dst] = relu(sum alpha*h[src] + b1) ----------------
__global__ __launch_bounds__(320) void aggregate1_kernel(const float* __restrict__ h,
                                                         const float* __restrict__ alpha,
                                                         const int* __restrict__ offs,
                                                         const int* __restrict__ srcs,
                                                         const float* __restrict__ bias,
                                                         float* __restrict__ out, int H, int C,
                                                         int HC) {
  int dstn = blockIdx.x;
  int t = threadIdx.x;
  int beg = offs[dstn], end = offs[dstn + 1];
  int nf4 = HC >> 2;
  const float4* b4 = (const float4*)bias;
  for (int fid = t; fid < nf4; fid += blockDim.x) {
    int hh = (fid << 2) / C;
    float4 acc = make_float4(0.f, 0.f, 0.f, 0.f);
    for (int j = beg; j < end; ++j) {
      int s = srcs[j];
      float al = alpha[(long)j * H + hh];
      float4 r = ((const float4*)(h + (long)s * HC))[fid];
      acc.x = fmaf(al, r.x, acc.x);
      acc.y = fmaf(al, r.y, acc.y);
      acc.z = fmaf(al, r.z, acc.z);
      acc.w = fmaf(al, r.w, acc.w);
    }
    float4 bb = b4[fid];
    acc.x = fmaxf(acc.x + bb.x, 0.f);
    acc.y = fmaxf(acc.y + bb.y, 0.f);
    acc.z = fmaxf(acc.z + bb.z, 0.f);
    acc.w = fmaxf(acc.w + bb.w, 0.f);
    ((float4*)(out + (long)dstn * HC))[fid] = acc;
  }
}

// ---------------- layer-2 aggregation with head-mean: out[dst,c] = relu(mean_h(...) + b2) ----
__global__ __launch_bounds__(128) void aggregate2_kernel(const float* __restrict__ h,
                                                         const float* __restrict__ alpha,
                                                         const int* __restrict__ offs,
                                                         const int* __restrict__ srcs,
                                                         const float* __restrict__ bias,
                                                         float* __restrict__ out, int H, int C) {
  int dstn = blockIdx.x;
  int c = threadIdx.x;
  if (c >= C) return;
  int beg = offs[dstn], end = offs[dstn + 1];
  int HC = H * C;
  float acc = 0.f;
  for (int j = beg; j < end; ++j) {
    int s = srcs[j];
    const float* row = h + (long)s * HC;
    const float* al = alpha + (long)j * H;
#pragma unroll 5
    for (int hh = 0; hh < H; ++hh) acc = fmaf(al[hh], row[hh * C + c], acc);
  }
  float v = acc * (1.f / (float)H) + bias[c];
  out[(long)dstn * C + c] = v > 0.f ? v : 0.f;
}

// ---------------- host ----------------
static inline size_t align256(size_t x) { return (x + 255) & ~(size_t)255; }

extern "C" void kernel_launch(void* const* d_in, const int* in_sizes, int n_in, void* d_out,
                              int out_size, void* d_ws, size_t ws_size, hipStream_t stream) {
  const float* x        = (const float*)d_in[0];
  const void*  ei       = d_in[1];
  const float* W1       = (const float*)d_in[2];
  const float* att_src1 = (const float*)d_in[3];
  const float* att_dst1 = (const float*)d_in[4];
  const float* b1       = (const float*)d_in[5];
  const float* W2       = (const float*)d_in[6];
  const float* att_src2 = (const float*)d_in[7];
  const float* att_dst2 = (const float*)d_in[8];
  const float* b2       = (const float*)d_in[9];
  float* out = (float*)d_out;

  const int C2  = in_sizes[9];            // 128
  const int H   = in_sizes[7] / C2;       // 20
  const int HC1 = in_sizes[5];            // 2560
  const int C1  = HC1 / H;                // 128
  const int G   = in_sizes[2] / HC1;      // 2000
  const int Nn  = in_sizes[0] / G;        // 10000
  const int E   = in_sizes[1] / 2;        // 100000
  const int HC2 = H * C2;                 // 2560
  const int Et  = E + Nn;
  const int HCmax = HC1 > HC2 ? HC1 : HC2;

  // workspace layout
  char* p = (char*)d_ws;
  size_t off = 0;
  float* h_pre = (float*)(p + off); off = align256(off + (size_t)Nn * HCmax * 4);
  float* x2    = (float*)(p + off); off = align256(off + (size_t)Nn * HC1 * 4);
  float* a_s   = (float*)(p + off); off = align256(off + (size_t)Nn * H * 4);
  float* a_d   = (float*)(p + off); off = align256(off + (size_t)Nn * H * 4);
  float* alpha = (float*)(p + off); off = align256(off + (size_t)Et * H * 4);
  int* cnt     = (int*)(p + off); off = align256(off + (size_t)Nn * 4);
  int* offs    = (int*)(p + off); off = align256(off + (size_t)(Nn + 1) * 4);
  int* fill    = (int*)(p + off); off = align256(off + (size_t)Nn * 4);
  int* srcs    = (int*)(p + off); off = align256(off + (size_t)Et * 4);
  int* flag64  = (int*)(p + off); off = align256(off + 16);
  (void)ws_size; (void)n_in; (void)out_size;

  const int TB = 256;
  // CSR build
  detect64_kernel<<<1, 1, 0, stream>>>((const unsigned int*)ei, flag64);
  init_cnt_kernel<<<(Nn + TB - 1) / TB, TB, 0, stream>>>(cnt, Nn);
  count_kernel<<<(E + TB - 1) / TB, TB, 0, stream>>>(ei, flag64, E, cnt);
  scan_kernel<<<1, 1024, 0, stream>>>(cnt, offs, Nn);
  init_self_kernel<<<(Nn + TB - 1) / TB, TB, 0, stream>>>(offs, srcs, fill, Nn);
  scatter_kernel<<<(E + TB - 1) / TB, TB, 0, stream>>>(ei, flag64, E, offs, fill, srcs);

  // layer 1
  {
    dim3 grid((Nn + BM - 1) / BM, HC1 / BN);
    sgemm_kernel<<<grid, 256, 0, stream>>>(x, W1, h_pre, Nn, HC1, G);
  }
  att_coef_kernel<<<(Nn + 3) / 4, 256, 0, stream>>>(h_pre, att_src1, att_dst1, a_s, a_d, Nn, H, C1);
  edge_softmax_kernel<<<(Nn * H + TB - 1) / TB, TB, 0, stream>>>(a_s, a_d, offs, srcs, alpha, Nn, H);
  aggregate1_kernel<<<Nn, 320, 0, stream>>>(h_pre, alpha, offs, srcs, b1, x2, H, C1, HC1);

  // layer 2
  {
    dim3 grid((Nn + BM - 1) / BM, HC2 / BN);
    sgemm_kernel<<<grid, 256, 0, stream>>>(x2, W2, h_pre, Nn, HC2, HC1);
  }
  att_coef_kernel<<<(Nn + 3) / 4, 256, 0, stream>>>(h_pre, att_src2, att_dst2, a_s, a_d, Nn, H, C2);
  edge_softmax_kernel<<<(Nn * H + TB - 1) / TB, TB, 0, stream>>>(a_s, a_d, offs, srcs, alpha, Nn, H);
  aggregate2_kernel<<<Nn, 128, 0, stream>>>(h_pre, alpha, offs, srcs, b2, out, H, C2);
}

// Round 2
// 1349.281 us; speedup vs baseline: 2.5990x; 2.5990x over previous
//
#include <hip/hip_runtime.h>

#define NEG_SLOPE 0.2f

typedef __attribute__((ext_vector_type(4))) float floatx4;
typedef __attribute__((ext_vector_type(8))) short shortx8;

__device__ __forceinline__ unsigned short f2bf(float f) {
  union { float f; unsigned int u; } v;
  v.f = f;
  unsigned int r = (v.u + 0x7FFFu + ((v.u >> 16) & 1u)) >> 16;
  return (unsigned short)r;
}

// ---------------- edge index width detection (int32 vs int64) ----------------
__device__ __forceinline__ int load_edge(const void* ei, long idx, int is64) {
  if (is64) return (int)((const long long*)ei)[idx];
  return ((const int*)ei)[idx];
}

__global__ void detect64_kernel(const unsigned int* __restrict__ p, int* __restrict__ flag) {
  int is64 = 1;
  for (int i = 0; i < 32; ++i)
    if (p[2 * i + 1] != 0u) is64 = 0;
  *flag = is64;
}

// ---------------- CSR build ----------------
__global__ void init_cnt_kernel(int* __restrict__ cnt, int n) {
  int i = blockIdx.x * blockDim.x + threadIdx.x;
  if (i < n) cnt[i] = 1;  // self-loop
}

__global__ void count_kernel(const void* __restrict__ ei, const int* __restrict__ flag, int E,
                             int* __restrict__ cnt) {
  int e = blockIdx.x * blockDim.x + threadIdx.x;
  if (e >= E) return;
  int is64 = *flag;
  int d = load_edge(ei, (long)E + e, is64);
  atomicAdd(&cnt[d], 1);
}

__global__ __launch_bounds__(1024) void scan_kernel(const int* __restrict__ cnt,
                                                    int* __restrict__ offs, int n) {
  __shared__ int partial[1024];
  int t = threadIdx.x;
  int per = (n + 1023) / 1024;
  int beg = t * per;
  int end = min(beg + per, n);
  int sum = 0;
  for (int i = beg; i < end; ++i) sum += cnt[i];
  partial[t] = sum;
  __syncthreads();
  for (int d = 1; d < 1024; d <<= 1) {
    int v = (t >= d) ? partial[t - d] : 0;
    __syncthreads();
    partial[t] += v;
    __syncthreads();
  }
  int excl = (t == 0) ? 0 : partial[t - 1];
  for (int i = beg; i < end; ++i) { offs[i] = excl; excl += cnt[i]; }
  if (t == 1023) offs[n] = partial[1023];
}

__global__ void init_self_kernel(const int* __restrict__ offs, int* __restrict__ srcs,
                                 int* __restrict__ fill, int n) {
  int i = blockIdx.x * blockDim.x + threadIdx.x;
  if (i < n) { srcs[offs[i]] = i; fill[i] = 1; }
}

__global__ void scatter_kernel(const void* __restrict__ ei, const int* __restrict__ flag, int E,
                               const int* __restrict__ offs, int* __restrict__ fill,
                               int* __restrict__ srcs) {
  int e = blockIdx.x * blockDim.x + threadIdx.x;
  if (e >= E) return;
  int is64 = *flag;
  int s = load_edge(ei, e, is64);
  int d = load_edge(ei, (long)E + e, is64);
  int pos = offs[d] + atomicAdd(&fill[d], 1);
  srcs[pos] = s;
}

// ---------------- casts ----------------
// A rows: fp32 [M][K] -> bf16 [.][Kpad], zero-padded in K. K%4==0.
__global__ __launch_bounds__(256) void cast_pad_kernel(const float* __restrict__ in,
                                                       unsigned short* __restrict__ out, int M,
                                                       int K, int Kpad) {
  long idx = (long)blockIdx.x * 256 + threadIdx.x;
  int cpr = Kpad >> 2;  // float4 chunks per row
  if (idx >= (long)M * cpr) return;
  int r = (int)(idx / cpr);
  int kc = (int)(idx - (long)r * cpr);
  int k = kc << 2;
  float4 v = make_float4(0.f, 0.f, 0.f, 0.f);
  if (k < K) v = *(const float4*)&in[(long)r * K + k];
  ushort4 o;
  o.x = f2bf(v.x); o.y = f2bf(v.y); o.z = f2bf(v.z); o.w = f2bf(v.w);
  *(ushort4*)&out[(long)r * Kpad + k] = o;
}

// W: fp32 [K][N] -> bf16 W^T [N][Kpad], zero-padded in K. N%32==0.
__global__ __launch_bounds__(256) void transpose_cast_kernel(const float* __restrict__ in,
                                                             unsigned short* __restrict__ out,
                                                             int K, int N, int Kpad) {
  __shared__ float tile[32][33];
  int kb = blockIdx.x * 32;
  int nb = blockIdx.y * 32;
  int tx = threadIdx.x & 31;
  int ty = threadIdx.x >> 5;  // 0..7
#pragma unroll
  for (int i = 0; i < 32; i += 8) {
    int k = kb + ty + i;
    tile[ty + i][tx] = (k < K) ? in[(long)k * N + nb + tx] : 0.f;
  }
  __syncthreads();
#pragma unroll
  for (int i = 0; i < 32; i += 8) {
    int n = nb + ty + i;
    out[(long)n * Kpad + kb + tx] = f2bf(tile[tx][ty + i]);
  }
}

// ---------------- bf16 MFMA GEMM: C[M,N] = A[M,K] * Bt[N,K]^T ----------------
// m97 structure: 128x128 tile, BK=32, 4 waves, 4x4 16x16x32 MFMA tiles each.
// LDS chunk-major layout [kc][row][8] so fragment ds_read_b128 is conflict-free
// and global_load_lds destinations are lane-linear. Requires K%32==0, N%128==0.
__global__ __launch_bounds__(256) void mfma_gemm_kernel(const unsigned short* __restrict__ A,
                                                        const unsigned short* __restrict__ Bt,
                                                        float* __restrict__ C, int M, int N,
                                                        int K) {
  __shared__ unsigned short As[128 * 32];
  __shared__ unsigned short Bs[128 * 32];

  int tid = threadIdx.x;
  int lane = tid & 63;
  int w = tid >> 6;  // wave 0..3
  int wm = w & 1, wn = w >> 1;
  int bm = blockIdx.x * 128;
  int bn = blockIdx.y * 128;
  int quad = lane >> 4;  // 0..3
  int l16 = lane & 15;

  floatx4 acc[4][4];
#pragma unroll
  for (int i = 0; i < 4; ++i)
#pragma unroll
    for (int j = 0; j < 4; ++j) acc[i][j] = (floatx4){0.f, 0.f, 0.f, 0.f};

  for (int k0 = 0; k0 < K; k0 += 32) {
    __syncthreads();
#pragma unroll
    for (int c = 0; c < 2; ++c) {
      int li = c * 256 + tid;   // chunk index: kc*128 + row
      int row = li & 127;
      int kc = li >> 7;
      const unsigned short* gA = A + (long)(bm + row) * K + k0 + kc * 8;
      __builtin_amdgcn_global_load_lds((const __attribute__((address_space(1))) void*)gA,
                                       (__attribute__((address_space(3))) void*)(As + li * 8), 16,
                                       0, 0);
      const unsigned short* gB = Bt + (long)(bn + row) * K + k0 + kc * 8;
      __builtin_amdgcn_global_load_lds((const __attribute__((address_space(1))) void*)gB,
                                       (__attribute__((address_space(3))) void*)(Bs + li * 8), 16,
                                       0, 0);
    }
    __syncthreads();
    shortx8 a[4], b[4];
#pragma unroll
    for (int i = 0; i < 4; ++i) {
      a[i] = *(const shortx8*)(As + (quad * 128 + wm * 64 + i * 16 + l16) * 8);
      b[i] = *(const shortx8*)(Bs + (quad * 128 + wn * 64 + i * 16 + l16) * 8);
    }
#pragma unroll
    for (int i = 0; i < 4; ++i)
#pragma unroll
      for (int j = 0; j < 4; ++j)
        acc[i][j] = __builtin_amdgcn_mfma_f32_16x16x32_bf16(a[i], b[j], acc[i][j], 0, 0, 0);
  }

  // epilogue: C/D layout col=lane&15, row=quad*4+reg
  int orow0 = bm + wm * 64 + quad * 4;
  int ocol0 = bn + wn * 64 + l16;
#pragma unroll
  for (int i = 0; i < 4; ++i)
#pragma unroll
    for (int j = 0; j < 4; ++j)
#pragma unroll
      for (int r = 0; r < 4; ++r) {
        int row = orow0 + i * 16 + r;
        if (row < M) C[(long)row * N + ocol0 + j * 16] = acc[i][j][r];
      }
}

// ---------------- attention coefficients: a_src/a_dst [N,H] ----------------
__global__ __launch_bounds__(256) void att_coef_kernel(const float* __restrict__ h,
                                                       const float* __restrict__ att_s,
                                                       const float* __restrict__ att_d,
                                                       float* __restrict__ a_s,
                                                       float* __restrict__ a_d, int n, int H,
                                                       int C) {
  int wave = (int)((blockIdx.x * blockDim.x + threadIdx.x) >> 6);
  int lane = threadIdx.x & 63;
  if (wave >= n) return;
  const float* row = h + (long)wave * H * C;
  for (int hh = 0; hh < H; ++hh) {
    float s = 0.f, d = 0.f;
    for (int c = lane; c < C; c += 64) {
      float v = row[hh * C + c];
      s += v * att_s[hh * C + c];
      d += v * att_d[hh * C + c];
    }
#pragma unroll
    for (int o = 32; o > 0; o >>= 1) {
      s += __shfl_down(s, o, 64);
      d += __shfl_down(d, o, 64);
    }
    if (lane == 0) {
      a_s[(long)wave * H + hh] = s;
      a_d[(long)wave * H + hh] = d;
    }
  }
}

// ---------------- per-(dst,head) segment softmax over CSR ----------------
__global__ void edge_softmax_kernel(const float* __restrict__ a_src,
                                    const float* __restrict__ a_dst,
                                    const int* __restrict__ offs, const int* __restrict__ srcs,
                                    float* __restrict__ alpha, int n, int H) {
  int idx = blockIdx.x * blockDim.x + threadIdx.x;
  if (idx >= n * H) return;
  int dstn = idx / H;
  int hh = idx - dstn * H;
  int beg = offs[dstn], end = offs[dstn + 1];
  float ad = a_dst[idx];
  float m = -1e30f;
  for (int j = beg; j < end; ++j) {
    float e = a_src[srcs[j] * H + hh] + ad;
    e = e > 0.f ? e : NEG_SLOPE * e;
    m = fmaxf(m, e);
  }
  float ssum = 0.f;
  for (int j = beg; j < end; ++j) {
    float e = a_src[srcs[j] * H + hh] + ad;
    e = e > 0.f ? e : NEG_SLOPE * e;
    float ex = __expf(e - m);
    alpha[(long)j * H + hh] = ex;
    ssum += ex;
  }
  float inv = 1.f / ssum;
  for (int j = beg; j < end; ++j) alpha[(long)j * H + hh] *= inv;
}

// ---------------- layer-1 aggregation -> bf16 (feeds GEMM2 directly) ----------------
__global__ __launch_bounds__(320) void aggregate1_kernel(const float* __restrict__ h,
                                                         const float* __restrict__ alpha,
                                                         const int* __restrict__ offs,
                                                         const int* __restrict__ srcs,
                                                         const float* __restrict__ bias,
                                                         unsigned short* __restrict__ out, int H,
                                                         int C, int HC) {
  int dstn = blockIdx.x;
  int t = threadIdx.x;
  int beg = offs[dstn], end = offs[dstn + 1];
  int nf4 = HC >> 2;
  const float4* b4 = (const float4*)bias;
  for (int fid = t; fid < nf4; fid += blockDim.x) {
    int hh = (fid << 2) / C;
    float4 acc = make_float4(0.f, 0.f, 0.f, 0.f);
    for (int j = beg; j < end; ++j) {
      int s = srcs[j];
      float al = alpha[(long)j * H + hh];
      float4 r = ((const float4*)(h + (long)s * HC))[fid];
      acc.x = fmaf(al, r.x, acc.x);
      acc.y = fmaf(al, r.y, acc.y);
      acc.z = fmaf(al, r.z, acc.z);
      acc.w = fmaf(al, r.w, acc.w);
    }
    float4 bb = b4[fid];
    ushort4 o;
    o.x = f2bf(fmaxf(acc.x + bb.x, 0.f));
    o.y = f2bf(fmaxf(acc.y + bb.y, 0.f));
    o.z = f2bf(fmaxf(acc.z + bb.z, 0.f));
    o.w = f2bf(fmaxf(acc.w + bb.w, 0.f));
    ((ushort4*)(out + (long)dstn * HC))[fid] = o;
  }
}

// ---------------- layer-2 aggregation with head-mean ----------------
__global__ __launch_bounds__(128) void aggregate2_kernel(const float* __restrict__ h,
                                                         const float* __restrict__ alpha,
                                                         const int* __restrict__ offs,
                                                         const int* __restrict__ srcs,
                                                         const float* __restrict__ bias,
                                                         float* __restrict__ out, int H, int C) {
  int dstn = blockIdx.x;
  int c = threadIdx.x;
  if (c >= C) return;
  int beg = offs[dstn], end = offs[dstn + 1];
  int HC = H * C;
  float acc = 0.f;
  for (int j = beg; j < end; ++j) {
    int s = srcs[j];
    const float* row = h + (long)s * HC;
    const float* al = alpha + (long)j * H;
#pragma unroll 5
    for (int hh = 0; hh < H; ++hh) acc = fmaf(al[hh], row[hh * C + c], acc);
  }
  float v = acc * (1.f / (float)H) + bias[c];
  out[(long)dstn * C + c] = v > 0.f ? v : 0.f;
}

// ---------------- host ----------------
static inline size_t align256(size_t x) { return (x + 255) & ~(size_t)255; }

extern "C" void kernel_launch(void* const* d_in, const int* in_sizes, int n_in, void* d_out,
                              int out_size, void* d_ws, size_t ws_size, hipStream_t stream) {
  const float* x        = (const float*)d_in[0];
  const void*  ei       = d_in[1];
  const float* W1       = (const float*)d_in[2];
  const float* att_src1 = (const float*)d_in[3];
  const float* att_dst1 = (const float*)d_in[4];
  const float* b1       = (const float*)d_in[5];
  const float* W2       = (const float*)d_in[6];
  const float* att_src2 = (const float*)d_in[7];
  const float* att_dst2 = (const float*)d_in[8];
  const float* b2       = (const float*)d_in[9];
  float* out = (float*)d_out;

  const int C2  = in_sizes[9];       // 128
  const int H   = in_sizes[7] / C2;  // 20
  const int HC1 = in_sizes[5];       // 2560
  const int C1  = HC1 / H;           // 128
  const int G   = in_sizes[2] / HC1; // 2000
  const int Nn  = in_sizes[0] / G;   // 10000
  const int E   = in_sizes[1] / 2;   // 100000
  const int HC2 = H * C2;            // 2560
  const int Et  = E + Nn;
  const int Mpad = ((Nn + 127) / 128) * 128;
  const int K1pad = ((G + 31) / 32) * 32;   // 2048 (G=2000)

  // workspace layout
  char* p = (char*)d_ws;
  size_t off = 0;
  float* h_pre = (float*)(p + off); off = align256(off + (size_t)Nn * (HC1 > HC2 ? HC1 : HC2) * 4);
  unsigned short* xb  = (unsigned short*)(p + off); off = align256(off + (size_t)Mpad * K1pad * 2);
  unsigned short* xb2 = (unsigned short*)(p + off); off = align256(off + (size_t)Mpad * HC1 * 2);
  unsigned short* W1t = (unsigned short*)(p + off); off = align256(off + (size_t)HC1 * K1pad * 2);
  unsigned short* W2t = (unsigned short*)(p + off); off = align256(off + (size_t)HC2 * HC1 * 2);
  float* a_s   = (float*)(p + off); off = align256(off + (size_t)Nn * H * 4);
  float* a_d   = (float*)(p + off); off = align256(off + (size_t)Nn * H * 4);
  float* alpha = (float*)(p + off); off = align256(off + (size_t)Et * H * 4);
  int* cnt     = (int*)(p + off); off = align256(off + (size_t)Nn * 4);
  int* offs    = (int*)(p + off); off = align256(off + (size_t)(Nn + 1) * 4);
  int* fill    = (int*)(p + off); off = align256(off + (size_t)Nn * 4);
  int* srcs    = (int*)(p + off); off = align256(off + (size_t)Et * 4);
  int* flag64  = (int*)(p + off); off = align256(off + 16);
  (void)ws_size; (void)n_in; (void)out_size;

  const int TB = 256;
  // CSR build
  detect64_kernel<<<1, 1, 0, stream>>>((const unsigned int*)ei, flag64);
  init_cnt_kernel<<<(Nn + TB - 1) / TB, TB, 0, stream>>>(cnt, Nn);
  count_kernel<<<(E + TB - 1) / TB, TB, 0, stream>>>(ei, flag64, E, cnt);
  scan_kernel<<<1, 1024, 0, stream>>>(cnt, offs, Nn);
  init_self_kernel<<<(Nn + TB - 1) / TB, TB, 0, stream>>>(offs, srcs, fill, Nn);
  scatter_kernel<<<(E + TB - 1) / TB, TB, 0, stream>>>(ei, flag64, E, offs, fill, srcs);

  // bf16 casts for layer-1 GEMM
  {
    long chunks = (long)Nn * (K1pad >> 2);
    cast_pad_kernel<<<(int)((chunks + 255) / 256), 256, 0, stream>>>(x, xb, Nn, G, K1pad);
    dim3 g1(K1pad / 32, HC1 / 32);
    transpose_cast_kernel<<<g1, 256, 0, stream>>>(W1, W1t, G, HC1, K1pad);
    dim3 g2(HC1 / 32, HC2 / 32);
    transpose_cast_kernel<<<g2, 256, 0, stream>>>(W2, W2t, HC1, HC2, HC1);
  }

  // layer 1
  {
    dim3 grid(Mpad / 128, HC1 / 128);
    mfma_gemm_kernel<<<grid, 256, 0, stream>>>(xb, W1t, h_pre, Nn, HC1, K1pad);
  }
  att_coef_kernel<<<(Nn + 3) / 4, 256, 0, stream>>>(h_pre, att_src1, att_dst1, a_s, a_d, Nn, H, C1);
  edge_softmax_kernel<<<(Nn * H + TB - 1) / TB, TB, 0, stream>>>(a_s, a_d, offs, srcs, alpha, Nn, H);
  aggregate1_kernel<<<Nn, 320, 0, stream>>>(h_pre, alpha, offs, srcs, b1, xb2, H, C1, HC1);

  // layer 2
  {
    dim3 grid(Mpad / 128, HC2 / 128);
    mfma_gemm_kernel<<<grid, 256, 0, stream>>>(xb2, W2t, h_pre, Nn, HC2, HC1);
  }
  att_coef_kernel<<<(Nn + 3) / 4, 256, 0, stream>>>(h_pre, att_src2, att_dst2, a_s, a_d, Nn, H, C2);
  edge_softmax_kernel<<<(Nn * H + TB - 1) / TB, TB, 0, stream>>>(a_s, a_d, offs, srcs, alpha, Nn, H);
  aggregate2_kernel<<<Nn, 128, 0, stream>>>(h_pre, alpha, offs, srcs, b2, out, H, C2);
}

// Round 3
// 1128.136 us; speedup vs baseline: 3.1085x; 1.1960x over previous
//
#include <hip/hip_runtime.h>

#define NEG_SLOPE 0.2f

typedef __attribute__((ext_vector_type(4))) float floatx4;
typedef __attribute__((ext_vector_type(8))) short shortx8;

__device__ __forceinline__ unsigned short f2bf(float f) {
  union { float f; unsigned int u; } v;
  v.f = f;
  unsigned int r = (v.u + 0x7FFFu + ((v.u >> 16) & 1u)) >> 16;
  return (unsigned short)r;
}
__device__ __forceinline__ float bf2f(unsigned short u) {
  union { unsigned int u; float f; } v;
  v.u = (unsigned int)u << 16;
  return v.f;
}
__device__ __forceinline__ void store_out(float* p, float v) { *p = v; }
__device__ __forceinline__ void store_out(unsigned short* p, float v) { *p = f2bf(v); }

// ---------------- edge index width detection (int32 vs int64) ----------------
__device__ __forceinline__ int load_edge(const void* ei, long idx, int is64) {
  if (is64) return (int)((const long long*)ei)[idx];
  return ((const int*)ei)[idx];
}

__global__ void detect64_kernel(const unsigned int* __restrict__ p, int* __restrict__ flag) {
  int is64 = 1;
  for (int i = 0; i < 32; ++i)
    if (p[2 * i + 1] != 0u) is64 = 0;
  *flag = is64;
}

// ---------------- CSR build ----------------
__global__ void init_cnt_kernel(int* __restrict__ cnt, int n) {
  int i = blockIdx.x * blockDim.x + threadIdx.x;
  if (i < n) cnt[i] = 1;  // self-loop
}

__global__ void count_kernel(const void* __restrict__ ei, const int* __restrict__ flag, int E,
                             int* __restrict__ cnt) {
  int e = blockIdx.x * blockDim.x + threadIdx.x;
  if (e >= E) return;
  int is64 = *flag;
  int d = load_edge(ei, (long)E + e, is64);
  atomicAdd(&cnt[d], 1);
}

__global__ __launch_bounds__(1024) void scan_kernel(const int* __restrict__ cnt,
                                                    int* __restrict__ offs, int n) {
  __shared__ int partial[1024];
  int t = threadIdx.x;
  int per = (n + 1023) / 1024;
  int beg = t * per;
  int end = min(beg + per, n);
  int sum = 0;
  for (int i = beg; i < end; ++i) sum += cnt[i];
  partial[t] = sum;
  __syncthreads();
  for (int d = 1; d < 1024; d <<= 1) {
    int v = (t >= d) ? partial[t - d] : 0;
    __syncthreads();
    partial[t] += v;
    __syncthreads();
  }
  int excl = (t == 0) ? 0 : partial[t - 1];
  for (int i = beg; i < end; ++i) { offs[i] = excl; excl += cnt[i]; }
  if (t == 1023) offs[n] = partial[1023];
}

__global__ void init_self_kernel(const int* __restrict__ offs, int* __restrict__ srcs,
                                 int* __restrict__ fill, int n) {
  int i = blockIdx.x * blockDim.x + threadIdx.x;
  if (i < n) { srcs[offs[i]] = i; fill[i] = 1; }
}

__global__ void scatter_kernel(const void* __restrict__ ei, const int* __restrict__ flag, int E,
                               const int* __restrict__ offs, int* __restrict__ fill,
                               int* __restrict__ srcs) {
  int e = blockIdx.x * blockDim.x + threadIdx.x;
  if (e >= E) return;
  int is64 = *flag;
  int s = load_edge(ei, e, is64);
  int d = load_edge(ei, (long)E + e, is64);
  int pos = offs[d] + atomicAdd(&fill[d], 1);
  srcs[pos] = s;
}

// ---------------- casts ----------------
__global__ __launch_bounds__(256) void cast_pad_kernel(const float* __restrict__ in,
                                                       unsigned short* __restrict__ out, int M,
                                                       int K, int Kpad) {
  long idx = (long)blockIdx.x * 256 + threadIdx.x;
  int cpr = Kpad >> 2;
  if (idx >= (long)M * cpr) return;
  int r = (int)(idx / cpr);
  int kc = (int)(idx - (long)r * cpr);
  int k = kc << 2;
  float4 v = make_float4(0.f, 0.f, 0.f, 0.f);
  if (k < K) v = *(const float4*)&in[(long)r * K + k];
  ushort4 o;
  o.x = f2bf(v.x); o.y = f2bf(v.y); o.z = f2bf(v.z); o.w = f2bf(v.w);
  *(ushort4*)&out[(long)r * Kpad + k] = o;
}

__global__ __launch_bounds__(256) void transpose_cast_kernel(const float* __restrict__ in,
                                                             unsigned short* __restrict__ out,
                                                             int K, int N, int Kpad) {
  __shared__ float tile[32][33];
  int kb = blockIdx.x * 32;
  int nb = blockIdx.y * 32;
  int tx = threadIdx.x & 31;
  int ty = threadIdx.x >> 5;
#pragma unroll
  for (int i = 0; i < 32; i += 8) {
    int k = kb + ty + i;
    tile[ty + i][tx] = (k < K) ? in[(long)k * N + nb + tx] : 0.f;
  }
  __syncthreads();
#pragma unroll
  for (int i = 0; i < 32; i += 8) {
    int n = nb + ty + i;
    out[(long)n * Kpad + kb + tx] = f2bf(tile[tx][ty + i]);
  }
}

// ---------------- bf16 MFMA GEMM, double-buffered LDS ----------------
// C[M,N] = A[M,K] * Bt[N,K]^T. blockIdx.x = N-tile (fastest -> L2/L3-friendly
// rounds of 13 M-tiles x all N-tiles), blockIdx.y = M-tile.
// K%32==0, N%128==0, A must have >= gridDim.y*128 rows allocated.
template <typename OT>
__global__ __launch_bounds__(256) void mfma_gemm_kernel(const unsigned short* __restrict__ A,
                                                        const unsigned short* __restrict__ Bt,
                                                        OT* __restrict__ C, int M, int N, int K) {
  __shared__ unsigned short As[2][128 * 32];
  __shared__ unsigned short Bs[2][128 * 32];

  int tid = threadIdx.x;
  int lane = tid & 63;
  int w = tid >> 6;
  int wm = w & 1, wn = w >> 1;
  int bn = blockIdx.x * 128;
  int bm = blockIdx.y * 128;
  int quad = lane >> 4;
  int l16 = lane & 15;

  const unsigned short* gA0 = A + (long)(bm + (tid & 127)) * K + (tid >> 7) * 8;
  const unsigned short* gB0 = Bt + (long)(bn + (tid & 127)) * K + (tid >> 7) * 8;

  floatx4 acc[4][4];
#pragma unroll
  for (int i = 0; i < 4; ++i)
#pragma unroll
    for (int j = 0; j < 4; ++j) acc[i][j] = (floatx4){0.f, 0.f, 0.f, 0.f};

  auto stage = [&](int k0, int b) {
#pragma unroll
    for (int c = 0; c < 2; ++c) {
      __builtin_amdgcn_global_load_lds(
          (const __attribute__((address_space(1))) void*)(gA0 + k0 + c * 16),
          (__attribute__((address_space(3))) void*)(&As[b][((c << 8) + tid) * 8]), 16, 0, 0);
      __builtin_amdgcn_global_load_lds(
          (const __attribute__((address_space(1))) void*)(gB0 + k0 + c * 16),
          (__attribute__((address_space(3))) void*)(&Bs[b][((c << 8) + tid) * 8]), 16, 0, 0);
    }
  };

  stage(0, 0);
  int nk = K >> 5;
  for (int k = 0; k < nk; ++k) {
    int cur = k & 1;
    // barrier drains every wave's outstanding global_load_lds (tile k resident)
    // and its LDS reads of tile k-1 (buffer k+1 overwrite safe).
    __syncthreads();
    if (k + 1 < nk) stage((k + 1) << 5, cur ^ 1);  // overlap: loads fly during compute
    shortx8 a[4], b[4];
#pragma unroll
    for (int i = 0; i < 4; ++i) {
      a[i] = *(const shortx8*)(&As[cur][(quad * 128 + wm * 64 + i * 16 + l16) * 8]);
      b[i] = *(const shortx8*)(&Bs[cur][(quad * 128 + wn * 64 + i * 16 + l16) * 8]);
    }
#pragma unroll
    for (int i = 0; i < 4; ++i)
#pragma unroll
      for (int j = 0; j < 4; ++j)
        acc[i][j] = __builtin_amdgcn_mfma_f32_16x16x32_bf16(a[i], b[j], acc[i][j], 0, 0, 0);
  }

  // epilogue: C/D layout col=lane&15, row=quad*4+reg
  int orow0 = bm + wm * 64 + quad * 4;
  int ocol0 = bn + wn * 64 + l16;
#pragma unroll
  for (int i = 0; i < 4; ++i)
#pragma unroll
    for (int j = 0; j < 4; ++j)
#pragma unroll
      for (int r = 0; r < 4; ++r) {
        int row = orow0 + i * 16 + r;
        if (row < M) store_out(&C[(long)row * N + ocol0 + j * 16], acc[i][j][r]);
      }
}

// ---------------- attention coefficients from bf16 h ----------------
__global__ __launch_bounds__(256) void att_coef_kernel(const unsigned short* __restrict__ h,
                                                       const float* __restrict__ att_s,
                                                       const float* __restrict__ att_d,
                                                       float* __restrict__ a_s,
                                                       float* __restrict__ a_d, int n, int H,
                                                       int C) {
  int wave = (int)((blockIdx.x * blockDim.x + threadIdx.x) >> 6);
  int lane = threadIdx.x & 63;
  if (wave >= n) return;
  const unsigned short* row = h + (long)wave * H * C;
  for (int hh = 0; hh < H; ++hh) {
    float s = 0.f, d = 0.f;
    for (int c = lane; c < C; c += 64) {
      float v = bf2f(row[hh * C + c]);
      s += v * att_s[hh * C + c];
      d += v * att_d[hh * C + c];
    }
#pragma unroll
    for (int o = 32; o > 0; o >>= 1) {
      s += __shfl_down(s, o, 64);
      d += __shfl_down(d, o, 64);
    }
    if (lane == 0) {
      a_s[(long)wave * H + hh] = s;
      a_d[(long)wave * H + hh] = d;
    }
  }
}

// ---------------- per-(dst,head) segment softmax over CSR ----------------
__global__ void edge_softmax_kernel(const float* __restrict__ a_src,
                                    const float* __restrict__ a_dst,
                                    const int* __restrict__ offs, const int* __restrict__ srcs,
                                    float* __restrict__ alpha, int n, int H) {
  int idx = blockIdx.x * blockDim.x + threadIdx.x;
  if (idx >= n * H) return;
  int dstn = idx / H;
  int hh = idx - dstn * H;
  int beg = offs[dstn], end = offs[dstn + 1];
  float ad = a_dst[idx];
  float m = -1e30f;
  for (int j = beg; j < end; ++j) {
    float e = a_src[srcs[j] * H + hh] + ad;
    e = e > 0.f ? e : NEG_SLOPE * e;
    m = fmaxf(m, e);
  }
  float ssum = 0.f;
  for (int j = beg; j < end; ++j) {
    float e = a_src[srcs[j] * H + hh] + ad;
    e = e > 0.f ? e : NEG_SLOPE * e;
    float ex = __expf(e - m);
    alpha[(long)j * H + hh] = ex;
    ssum += ex;
  }
  float inv = 1.f / ssum;
  for (int j = beg; j < end; ++j) alpha[(long)j * H + hh] *= inv;
}

// ---------------- layer-1 aggregation: bf16 h -> bf16 x2 ----------------
__global__ __launch_bounds__(320) void aggregate1_kernel(const unsigned short* __restrict__ h,
                                                         const float* __restrict__ alpha,
                                                         const int* __restrict__ offs,
                                                         const int* __restrict__ srcs,
                                                         const float* __restrict__ bias,
                                                         unsigned short* __restrict__ out, int H,
                                                         int C, int HC) {
  int dstn = blockIdx.x;
  int t = threadIdx.x;
  int beg = offs[dstn], end = offs[dstn + 1];
  int nf4 = HC >> 2;
  const float4* b4 = (const float4*)bias;
  for (int fid = t; fid < nf4; fid += blockDim.x) {
    int hh = (fid << 2) / C;
    float4 acc = make_float4(0.f, 0.f, 0.f, 0.f);
    for (int j = beg; j < end; ++j) {
      int s = srcs[j];
      float al = alpha[(long)j * H + hh];
      ushort4 r = ((const ushort4*)(h + (long)s * HC))[fid];
      acc.x = fmaf(al, bf2f(r.x), acc.x);
      acc.y = fmaf(al, bf2f(r.y), acc.y);
      acc.z = fmaf(al, bf2f(r.z), acc.z);
      acc.w = fmaf(al, bf2f(r.w), acc.w);
    }
    float4 bb = b4[fid];
    ushort4 o;
    o.x = f2bf(fmaxf(acc.x + bb.x, 0.f));
    o.y = f2bf(fmaxf(acc.y + bb.y, 0.f));
    o.z = f2bf(fmaxf(acc.z + bb.z, 0.f));
    o.w = f2bf(fmaxf(acc.w + bb.w, 0.f));
    ((ushort4*)(out + (long)dstn * HC))[fid] = o;
  }
}

// ---------------- layer-2 aggregation with head-mean: bf16 h -> fp32 out ----------------
__global__ __launch_bounds__(128) void aggregate2_kernel(const unsigned short* __restrict__ h,
                                                         const float* __restrict__ alpha,
                                                         const int* __restrict__ offs,
                                                         const int* __restrict__ srcs,
                                                         const float* __restrict__ bias,
                                                         float* __restrict__ out, int H, int C) {
  int dstn = blockIdx.x;
  int c = threadIdx.x;
  if (c >= C) return;
  int beg = offs[dstn], end = offs[dstn + 1];
  int HC = H * C;
  float acc = 0.f;
  for (int j = beg; j < end; ++j) {
    int s = srcs[j];
    const unsigned short* row = h + (long)s * HC;
    const float* al = alpha + (long)j * H;
#pragma unroll 5
    for (int hh = 0; hh < H; ++hh) acc = fmaf(al[hh], bf2f(row[hh * C + c]), acc);
  }
  float v = acc * (1.f / (float)H) + bias[c];
  out[(long)dstn * C + c] = v > 0.f ? v : 0.f;
}

// ---------------- host ----------------
static inline size_t align256(size_t x) { return (x + 255) & ~(size_t)255; }

extern "C" void kernel_launch(void* const* d_in, const int* in_sizes, int n_in, void* d_out,
                              int out_size, void* d_ws, size_t ws_size, hipStream_t stream) {
  const float* x        = (const float*)d_in[0];
  const void*  ei       = d_in[1];
  const float* W1       = (const float*)d_in[2];
  const float* att_src1 = (const float*)d_in[3];
  const float* att_dst1 = (const float*)d_in[4];
  const float* b1       = (const float*)d_in[5];
  const float* W2       = (const float*)d_in[6];
  const float* att_src2 = (const float*)d_in[7];
  const float* att_dst2 = (const float*)d_in[8];
  const float* b2       = (const float*)d_in[9];
  float* out = (float*)d_out;

  const int C2  = in_sizes[9];       // 128
  const int H   = in_sizes[7] / C2;  // 20
  const int HC1 = in_sizes[5];       // 2560
  const int C1  = HC1 / H;           // 128
  const int G   = in_sizes[2] / HC1; // 2000
  const int Nn  = in_sizes[0] / G;   // 10000
  const int E   = in_sizes[1] / 2;   // 100000
  const int HC2 = H * C2;            // 2560
  const int Et  = E + Nn;
  const int Mpad = ((Nn + 127) / 128) * 128;
  const int K1pad = ((G + 31) / 32) * 32;  // 2048

  // workspace layout
  char* p = (char*)d_ws;
  size_t off = 0;
  unsigned short* hb  = (unsigned short*)(p + off); off = align256(off + (size_t)Mpad * (HC1 > HC2 ? HC1 : HC2) * 2);
  unsigned short* xb  = (unsigned short*)(p + off); off = align256(off + (size_t)Mpad * K1pad * 2);
  unsigned short* xb2 = (unsigned short*)(p + off); off = align256(off + (size_t)Mpad * HC1 * 2);
  unsigned short* W1t = (unsigned short*)(p + off); off = align256(off + (size_t)HC1 * K1pad * 2);
  unsigned short* W2t = (unsigned short*)(p + off); off = align256(off + (size_t)HC2 * HC1 * 2);
  float* a_s   = (float*)(p + off); off = align256(off + (size_t)Nn * H * 4);
  float* a_d   = (float*)(p + off); off = align256(off + (size_t)Nn * H * 4);
  float* alpha = (float*)(p + off); off = align256(off + (size_t)Et * H * 4);
  int* cnt     = (int*)(p + off); off = align256(off + (size_t)Nn * 4);
  int* offs    = (int*)(p + off); off = align256(off + (size_t)(Nn + 1) * 4);
  int* fill    = (int*)(p + off); off = align256(off + (size_t)Nn * 4);
  int* srcs    = (int*)(p + off); off = align256(off + (size_t)Et * 4);
  int* flag64  = (int*)(p + off); off = align256(off + 16);
  (void)ws_size; (void)n_in; (void)out_size;

  const int TB = 256;
  // CSR build
  detect64_kernel<<<1, 1, 0, stream>>>((const unsigned int*)ei, flag64);
  init_cnt_kernel<<<(Nn + TB - 1) / TB, TB, 0, stream>>>(cnt, Nn);
  count_kernel<<<(E + TB - 1) / TB, TB, 0, stream>>>(ei, flag64, E, cnt);
  scan_kernel<<<1, 1024, 0, stream>>>(cnt, offs, Nn);
  init_self_kernel<<<(Nn + TB - 1) / TB, TB, 0, stream>>>(offs, srcs, fill, Nn);
  scatter_kernel<<<(E + TB - 1) / TB, TB, 0, stream>>>(ei, flag64, E, offs, fill, srcs);

  // bf16 casts
  {
    long chunks = (long)Nn * (K1pad >> 2);
    cast_pad_kernel<<<(int)((chunks + 255) / 256), 256, 0, stream>>>(x, xb, Nn, G, K1pad);
    dim3 g1(K1pad / 32, HC1 / 32);
    transpose_cast_kernel<<<g1, 256, 0, stream>>>(W1, W1t, G, HC1, K1pad);
    dim3 g2(HC1 / 32, HC2 / 32);
    transpose_cast_kernel<<<g2, 256, 0, stream>>>(W2, W2t, HC1, HC2, HC1);
  }

  // layer 1
  {
    dim3 grid(HC1 / 128, Mpad / 128);  // N-tile fastest
    mfma_gemm_kernel<unsigned short><<<grid, 256, 0, stream>>>(xb, W1t, hb, Nn, HC1, K1pad);
  }
  att_coef_kernel<<<(Nn + 3) / 4, 256, 0, stream>>>(hb, att_src1, att_dst1, a_s, a_d, Nn, H, C1);
  edge_softmax_kernel<<<(Nn * H + TB - 1) / TB, TB, 0, stream>>>(a_s, a_d, offs, srcs, alpha, Nn, H);
  aggregate1_kernel<<<Nn, 320, 0, stream>>>(hb, alpha, offs, srcs, b1, xb2, H, C1, HC1);

  // layer 2
  {
    dim3 grid(HC2 / 128, Mpad / 128);
    mfma_gemm_kernel<unsigned short><<<grid, 256, 0, stream>>>(xb2, W2t, hb, Nn, HC2, HC1);
  }
  att_coef_kernel<<<(Nn + 3) / 4, 256, 0, stream>>>(hb, att_src2, att_dst2, a_s, a_d, Nn, H, C2);
  edge_softmax_kernel<<<(Nn * H + TB - 1) / TB, TB, 0, stream>>>(a_s, a_d, offs, srcs, alpha, Nn, H);
  aggregate2_kernel<<<Nn, 128, 0, stream>>>(hb, alpha, offs, srcs, b2, out, H, C2);
}

// Round 4
// 1099.846 us; speedup vs baseline: 3.1884x; 1.0257x over previous
//
#include <hip/hip_runtime.h>

#define NEG_SLOPE 0.2f

typedef __attribute__((ext_vector_type(4))) float floatx4;
typedef __attribute__((ext_vector_type(8))) short shortx8;

__device__ __forceinline__ unsigned short f2bf(float f) {
  union { float f; unsigned int u; } v;
  v.f = f;
  unsigned int r = (v.u + 0x7FFFu + ((v.u >> 16) & 1u)) >> 16;
  return (unsigned short)r;
}
__device__ __forceinline__ float bf2f(unsigned short u) {
  union { unsigned int u; float f; } v;
  v.u = (unsigned int)u << 16;
  return v.f;
}
__device__ __forceinline__ void store_out(float* p, float v) { *p = v; }
__device__ __forceinline__ void store_out(unsigned short* p, float v) { *p = f2bf(v); }

// ---------------- edge index width detection (int32 vs int64) ----------------
__device__ __forceinline__ int load_edge(const void* ei, long idx, int is64) {
  if (is64) return (int)((const long long*)ei)[idx];
  return ((const int*)ei)[idx];
}

__global__ void detect64_kernel(const unsigned int* __restrict__ p, int* __restrict__ flag) {
  int is64 = 1;
  for (int i = 0; i < 32; ++i)
    if (p[2 * i + 1] != 0u) is64 = 0;
  *flag = is64;
}

// ---------------- CSR build ----------------
__global__ void init_cnt_kernel(int* __restrict__ cnt, int n) {
  int i = blockIdx.x * blockDim.x + threadIdx.x;
  if (i < n) cnt[i] = 1;  // self-loop
}

__global__ void count_kernel(const void* __restrict__ ei, const int* __restrict__ flag, int E,
                             int* __restrict__ cnt) {
  int e = blockIdx.x * blockDim.x + threadIdx.x;
  if (e >= E) return;
  int is64 = *flag;
  int d = load_edge(ei, (long)E + e, is64);
  atomicAdd(&cnt[d], 1);
}

__global__ __launch_bounds__(1024) void scan_kernel(const int* __restrict__ cnt,
                                                    int* __restrict__ offs, int n) {
  __shared__ int partial[1024];
  int t = threadIdx.x;
  int per = (n + 1023) / 1024;
  int beg = t * per;
  int end = min(beg + per, n);
  int sum = 0;
  for (int i = beg; i < end; ++i) sum += cnt[i];
  partial[t] = sum;
  __syncthreads();
  for (int d = 1; d < 1024; d <<= 1) {
    int v = (t >= d) ? partial[t - d] : 0;
    __syncthreads();
    partial[t] += v;
    __syncthreads();
  }
  int excl = (t == 0) ? 0 : partial[t - 1];
  for (int i = beg; i < end; ++i) { offs[i] = excl; excl += cnt[i]; }
  if (t == 1023) offs[n] = partial[1023];
}

__global__ void init_self_kernel(const int* __restrict__ offs, int* __restrict__ srcs,
                                 int* __restrict__ fill, int n) {
  int i = blockIdx.x * blockDim.x + threadIdx.x;
  if (i < n) { srcs[offs[i]] = i; fill[i] = 1; }
}

__global__ void scatter_kernel(const void* __restrict__ ei, const int* __restrict__ flag, int E,
                               const int* __restrict__ offs, int* __restrict__ fill,
                               int* __restrict__ srcs) {
  int e = blockIdx.x * blockDim.x + threadIdx.x;
  if (e >= E) return;
  int is64 = *flag;
  int s = load_edge(ei, e, is64);
  int d = load_edge(ei, (long)E + e, is64);
  int pos = offs[d] + atomicAdd(&fill[d], 1);
  srcs[pos] = s;
}

// ---------------- casts ----------------
__global__ __launch_bounds__(256) void cast_pad_kernel(const float* __restrict__ in,
                                                       unsigned short* __restrict__ out, int M,
                                                       int K, int Kpad) {
  long idx = (long)blockIdx.x * 256 + threadIdx.x;
  int cpr = Kpad >> 2;
  if (idx >= (long)M * cpr) return;
  int r = (int)(idx / cpr);
  int kc = (int)(idx - (long)r * cpr);
  int k = kc << 2;
  float4 v = make_float4(0.f, 0.f, 0.f, 0.f);
  if (k < K) v = *(const float4*)&in[(long)r * K + k];
  ushort4 o;
  o.x = f2bf(v.x); o.y = f2bf(v.y); o.z = f2bf(v.z); o.w = f2bf(v.w);
  *(ushort4*)&out[(long)r * Kpad + k] = o;
}

__global__ __launch_bounds__(256) void transpose_cast_kernel(const float* __restrict__ in,
                                                             unsigned short* __restrict__ out,
                                                             int K, int N, int Kpad) {
  __shared__ float tile[32][33];
  int kb = blockIdx.x * 32;
  int nb = blockIdx.y * 32;
  int tx = threadIdx.x & 31;
  int ty = threadIdx.x >> 5;
#pragma unroll
  for (int i = 0; i < 32; i += 8) {
    int k = kb + ty + i;
    tile[ty + i][tx] = (k < K) ? in[(long)k * N + nb + tx] : 0.f;
  }
  __syncthreads();
#pragma unroll
  for (int i = 0; i < 32; i += 8) {
    int n = nb + ty + i;
    out[(long)n * Kpad + kb + tx] = f2bf(tile[tx][ty + i]);
  }
}

// ---------------- bf16 MFMA GEMM, double-buffered LDS ----------------
// C[M,N] = A[M,K] * Bt[N,K]^T. blockIdx.x = N-tile (fastest), blockIdx.y = M-tile.
// K%32==0, N%128==0, A must have >= gridDim.y*128 rows allocated.
// Loop order: barrier -> ds_read fragments (cur) -> issue DMA (next) -> MFMA.
// ds_read BEFORE the next-tile global_load_lds issue, so an alias-conservative
// vmcnt wait before ds_read only covers already-drained loads (dbuf actually
// overlaps; the DMA flies during the MFMA phase).
template <typename OT>
__global__ __launch_bounds__(256) void mfma_gemm_kernel(const unsigned short* __restrict__ A,
                                                        const unsigned short* __restrict__ Bt,
                                                        OT* __restrict__ C, int M, int N, int K) {
  __shared__ unsigned short As[2][128 * 32];
  __shared__ unsigned short Bs[2][128 * 32];

  int tid = threadIdx.x;
  int lane = tid & 63;
  int w = tid >> 6;
  int wm = w & 1, wn = w >> 1;
  int bn = blockIdx.x * 128;
  int bm = blockIdx.y * 128;
  int quad = lane >> 4;
  int l16 = lane & 15;

  const unsigned short* gA0 = A + (long)(bm + (tid & 127)) * K + (tid >> 7) * 8;
  const unsigned short* gB0 = Bt + (long)(bn + (tid & 127)) * K + (tid >> 7) * 8;

  floatx4 acc[4][4];
#pragma unroll
  for (int i = 0; i < 4; ++i)
#pragma unroll
    for (int j = 0; j < 4; ++j) acc[i][j] = (floatx4){0.f, 0.f, 0.f, 0.f};

  auto stage = [&](int k0, int b) {
#pragma unroll
    for (int c = 0; c < 2; ++c) {
      __builtin_amdgcn_global_load_lds(
          (const __attribute__((address_space(1))) void*)(gA0 + k0 + c * 16),
          (__attribute__((address_space(3))) void*)(&As[b][((c << 8) + tid) * 8]), 16, 0, 0);
      __builtin_amdgcn_global_load_lds(
          (const __attribute__((address_space(1))) void*)(gB0 + k0 + c * 16),
          (__attribute__((address_space(3))) void*)(&Bs[b][((c << 8) + tid) * 8]), 16, 0, 0);
    }
  };

  stage(0, 0);
  int nk = K >> 5;
  for (int k = 0; k < nk; ++k) {
    int cur = k & 1;
    // barrier drains the DMA issued last iteration (tile k now resident) and
    // orders all waves' reads of buffer cur^1 before we overwrite it below.
    __syncthreads();
    shortx8 a[4], b[4];
#pragma unroll
    for (int i = 0; i < 4; ++i) {
      a[i] = *(const shortx8*)(&As[cur][(quad * 128 + wm * 64 + i * 16 + l16) * 8]);
      b[i] = *(const shortx8*)(&Bs[cur][(quad * 128 + wn * 64 + i * 16 + l16) * 8]);
    }
    if (k + 1 < nk) stage((k + 1) << 5, cur ^ 1);  // flies during MFMA phase
#pragma unroll
    for (int i = 0; i < 4; ++i)
#pragma unroll
      for (int j = 0; j < 4; ++j)
        acc[i][j] = __builtin_amdgcn_mfma_f32_16x16x32_bf16(a[i], b[j], acc[i][j], 0, 0, 0);
  }

  // epilogue: C/D layout col=lane&15, row=quad*4+reg
  int orow0 = bm + wm * 64 + quad * 4;
  int ocol0 = bn + wn * 64 + l16;
#pragma unroll
  for (int i = 0; i < 4; ++i)
#pragma unroll
    for (int j = 0; j < 4; ++j)
#pragma unroll
      for (int r = 0; r < 4; ++r) {
        int row = orow0 + i * 16 + r;
        if (row < M) store_out(&C[(long)row * N + ocol0 + j * 16], acc[i][j][r]);
      }
}

// ---------------- attention coefficients from bf16 h ----------------
__global__ __launch_bounds__(256) void att_coef_kernel(const unsigned short* __restrict__ h,
                                                       const float* __restrict__ att_s,
                                                       const float* __restrict__ att_d,
                                                       float* __restrict__ a_s,
                                                       float* __restrict__ a_d, int n, int H,
                                                       int C) {
  int wave = (int)((blockIdx.x * blockDim.x + threadIdx.x) >> 6);
  int lane = threadIdx.x & 63;
  if (wave >= n) return;
  const unsigned short* row = h + (long)wave * H * C;
  for (int hh = 0; hh < H; ++hh) {
    float s = 0.f, d = 0.f;
    for (int c = lane; c < C; c += 64) {
      float v = bf2f(row[hh * C + c]);
      s += v * att_s[hh * C + c];
      d += v * att_d[hh * C + c];
    }
#pragma unroll
    for (int o = 32; o > 0; o >>= 1) {
      s += __shfl_down(s, o, 64);
      d += __shfl_down(d, o, 64);
    }
    if (lane == 0) {
      a_s[(long)wave * H + hh] = s;
      a_d[(long)wave * H + hh] = d;
    }
  }
}

// ---------------- per-(dst,head) segment softmax over CSR ----------------
__global__ void edge_softmax_kernel(const float* __restrict__ a_src,
                                    const float* __restrict__ a_dst,
                                    const int* __restrict__ offs, const int* __restrict__ srcs,
                                    float* __restrict__ alpha, int n, int H) {
  int idx = blockIdx.x * blockDim.x + threadIdx.x;
  if (idx >= n * H) return;
  int dstn = idx / H;
  int hh = idx - dstn * H;
  int beg = offs[dstn], end = offs[dstn + 1];
  float ad = a_dst[idx];
  float m = -1e30f;
  for (int j = beg; j < end; ++j) {
    float e = a_src[srcs[j] * H + hh] + ad;
    e = e > 0.f ? e : NEG_SLOPE * e;
    m = fmaxf(m, e);
  }
  float ssum = 0.f;
  for (int j = beg; j < end; ++j) {
    float e = a_src[srcs[j] * H + hh] + ad;
    e = e > 0.f ? e : NEG_SLOPE * e;
    float ex = __expf(e - m);
    alpha[(long)j * H + hh] = ex;
    ssum += ex;
  }
  float inv = 1.f / ssum;
  for (int j = beg; j < end; ++j) alpha[(long)j * H + hh] *= inv;
}

// ---------------- layer-1 aggregation: bf16 h -> bf16 x2, 16B vector loads ----------------
__global__ __launch_bounds__(320) void aggregate1_kernel(const unsigned short* __restrict__ h,
                                                         const float* __restrict__ alpha,
                                                         const int* __restrict__ offs,
                                                         const int* __restrict__ srcs,
                                                         const float* __restrict__ bias,
                                                         unsigned short* __restrict__ out, int H,
                                                         int C, int HC) {
  int dstn = blockIdx.x;
  int t = threadIdx.x;
  int beg = offs[dstn], end = offs[dstn + 1];
  int nf8 = HC >> 3;  // 16B chunks per row
  for (int fid = t; fid < nf8; fid += blockDim.x) {
    int hh = (fid << 3) / C;
    float acc[8];
#pragma unroll
    for (int i = 0; i < 8; ++i) acc[i] = 0.f;
    for (int j = beg; j < end; ++j) {
      int s = srcs[j];
      float al = alpha[(long)j * H + hh];
      shortx8 r = ((const shortx8*)(h + (long)s * HC))[fid];
#pragma unroll
      for (int i = 0; i < 8; ++i) acc[i] = fmaf(al, bf2f((unsigned short)r[i]), acc[i]);
    }
    shortx8 o;
#pragma unroll
    for (int i = 0; i < 8; ++i) {
      float bb = bias[(fid << 3) + i];
      o[i] = (short)f2bf(fmaxf(acc[i] + bb, 0.f));
    }
    ((shortx8*)(out + (long)dstn * HC))[fid] = o;
  }
}

// ---------------- layer-2 aggregation with head-mean: bf16 h -> fp32 out ----------------
__global__ __launch_bounds__(128) void aggregate2_kernel(const unsigned short* __restrict__ h,
                                                         const float* __restrict__ alpha,
                                                         const int* __restrict__ offs,
                                                         const int* __restrict__ srcs,
                                                         const float* __restrict__ bias,
                                                         float* __restrict__ out, int H, int C) {
  int dstn = blockIdx.x;
  int c = threadIdx.x;
  if (c >= C) return;
  int beg = offs[dstn], end = offs[dstn + 1];
  int HC = H * C;
  float acc = 0.f;
  for (int j = beg; j < end; ++j) {
    int s = srcs[j];
    const unsigned short* row = h + (long)s * HC;
    const float* al = alpha + (long)j * H;
#pragma unroll 5
    for (int hh = 0; hh < H; ++hh) acc = fmaf(al[hh], bf2f(row[hh * C + c]), acc);
  }
  float v = acc * (1.f / (float)H) + bias[c];
  out[(long)dstn * C + c] = v > 0.f ? v : 0.f;
}

// ---------------- host ----------------
static inline size_t align256(size_t x) { return (x + 255) & ~(size_t)255; }

extern "C" void kernel_launch(void* const* d_in, const int* in_sizes, int n_in, void* d_out,
                              int out_size, void* d_ws, size_t ws_size, hipStream_t stream) {
  const float* x        = (const float*)d_in[0];
  const void*  ei       = d_in[1];
  const float* W1       = (const float*)d_in[2];
  const float* att_src1 = (const float*)d_in[3];
  const float* att_dst1 = (const float*)d_in[4];
  const float* b1       = (const float*)d_in[5];
  const float* W2       = (const float*)d_in[6];
  const float* att_src2 = (const float*)d_in[7];
  const float* att_dst2 = (const float*)d_in[8];
  const float* b2       = (const float*)d_in[9];
  float* out = (float*)d_out;

  const int C2  = in_sizes[9];       // 128
  const int H   = in_sizes[7] / C2;  // 20
  const int HC1 = in_sizes[5];       // 2560
  const int C1  = HC1 / H;           // 128
  const int G   = in_sizes[2] / HC1; // 2000
  const int Nn  = in_sizes[0] / G;   // 10000
  const int E   = in_sizes[1] / 2;   // 100000
  const int HC2 = H * C2;            // 2560
  const int Et  = E + Nn;
  const int Mpad = ((Nn + 127) / 128) * 128;
  const int K1pad = ((G + 31) / 32) * 32;  // 2048

  // workspace layout
  char* p = (char*)d_ws;
  size_t off = 0;
  unsigned short* hb  = (unsigned short*)(p + off); off = align256(off + (size_t)Mpad * (HC1 > HC2 ? HC1 : HC2) * 2);
  unsigned short* xb  = (unsigned short*)(p + off); off = align256(off + (size_t)Mpad * K1pad * 2);
  unsigned short* xb2 = (unsigned short*)(p + off); off = align256(off + (size_t)Mpad * HC1 * 2);
  unsigned short* W1t = (unsigned short*)(p + off); off = align256(off + (size_t)HC1 * K1pad * 2);
  unsigned short* W2t = (unsigned short*)(p + off); off = align256(off + (size_t)HC2 * HC1 * 2);
  float* a_s   = (float*)(p + off); off = align256(off + (size_t)Nn * H * 4);
  float* a_d   = (float*)(p + off); off = align256(off + (size_t)Nn * H * 4);
  float* alpha = (float*)(p + off); off = align256(off + (size_t)Et * H * 4);
  int* cnt     = (int*)(p + off); off = align256(off + (size_t)Nn * 4);
  int* offs    = (int*)(p + off); off = align256(off + (size_t)(Nn + 1) * 4);
  int* fill    = (int*)(p + off); off = align256(off + (size_t)Nn * 4);
  int* srcs    = (int*)(p + off); off = align256(off + (size_t)Et * 4);
  int* flag64  = (int*)(p + off); off = align256(off + 16);
  (void)ws_size; (void)n_in; (void)out_size;

  const int TB = 256;
  // CSR build
  detect64_kernel<<<1, 1, 0, stream>>>((const unsigned int*)ei, flag64);
  init_cnt_kernel<<<(Nn + TB - 1) / TB, TB, 0, stream>>>(cnt, Nn);
  count_kernel<<<(E + TB - 1) / TB, TB, 0, stream>>>(ei, flag64, E, cnt);
  scan_kernel<<<1, 1024, 0, stream>>>(cnt, offs, Nn);
  init_self_kernel<<<(Nn + TB - 1) / TB, TB, 0, stream>>>(offs, srcs, fill, Nn);
  scatter_kernel<<<(E + TB - 1) / TB, TB, 0, stream>>>(ei, flag64, E, offs, fill, srcs);

  // bf16 casts
  {
    long chunks = (long)Nn * (K1pad >> 2);
    cast_pad_kernel<<<(int)((chunks + 255) / 256), 256, 0, stream>>>(x, xb, Nn, G, K1pad);
    dim3 g1(K1pad / 32, HC1 / 32);
    transpose_cast_kernel<<<g1, 256, 0, stream>>>(W1, W1t, G, HC1, K1pad);
    dim3 g2(HC1 / 32, HC2 / 32);
    transpose_cast_kernel<<<g2, 256, 0, stream>>>(W2, W2t, HC1, HC2, HC1);
  }

  // layer 1
  {
    dim3 grid(HC1 / 128, Mpad / 128);  // N-tile fastest
    mfma_gemm_kernel<unsigned short><<<grid, 256, 0, stream>>>(xb, W1t, hb, Nn, HC1, K1pad);
  }
  att_coef_kernel<<<(Nn + 3) / 4, 256, 0, stream>>>(hb, att_src1, att_dst1, a_s, a_d, Nn, H, C1);
  edge_softmax_kernel<<<(Nn * H + TB - 1) / TB, TB, 0, stream>>>(a_s, a_d, offs, srcs, alpha, Nn, H);
  aggregate1_kernel<<<Nn, 320, 0, stream>>>(hb, alpha, offs, srcs, b1, xb2, H, C1, HC1);

  // layer 2
  {
    dim3 grid(HC2 / 128, Mpad / 128);
    mfma_gemm_kernel<unsigned short><<<grid, 256, 0, stream>>>(xb2, W2t, hb, Nn, HC2, HC1);
  }
  att_coef_kernel<<<(Nn + 3) / 4, 256, 0, stream>>>(hb, att_src2, att_dst2, a_s, a_d, Nn, H, C2);
  edge_softmax_kernel<<<(Nn * H + TB - 1) / TB, TB, 0, stream>>>(a_s, a_d, offs, srcs, alpha, Nn, H);
  aggregate2_kernel<<<Nn, 128, 0, stream>>>(hb, alpha, offs, srcs, b2, out, H, C2);
}